// Round 8
// baseline (131.994 us; speedup 1.0000x reference)
//
#include <hip/hip_runtime.h>

// SparseProductLayer:  out = x @ (M0*M1*M2)^T + bias
// Pipeline: multi-block CSR build -> entry-wise Mc build -> x->bf16 ->
// MFMA GEMM with A-operand DIRECT FROM GLOBAL (L1/L2-served, no LDS),
// B through a 4-slot LDS ring (64 KiB), counted vmcnt, involution swizzle,
// setprio. BM=128,BN=256,BK=32, 8 waves, 256 blocks = 1/CU.
//
// d_ws layout (bytes):
//   [0)         Mc  bf16 [D][D]     8388608
//   [8388608)   Xb  bf16 [B][D]    16777216
//   [25165824)  CSR: off[3][2052], cur[3][2048], col[3][16384], val[3][16384]

#define BATCH 4096
#define DIM   2048
#define NNZc  16384
#define NT    256

typedef short bf16x8 __attribute__((ext_vector_type(8)));
typedef float f32x4  __attribute__((ext_vector_type(4)));

__device__ __forceinline__ unsigned short f2bf(float f) {
    unsigned u = __float_as_uint(f);
    unsigned r = (u + 0x7fffu + ((u >> 16) & 1u)) >> 16;   // RNE
    return (unsigned short)r;
}

__device__ __forceinline__ void gload16(const void* g, void* l) {
    __builtin_amdgcn_global_load_lds((const __attribute__((address_space(1))) void*)g,
                                     (__attribute__((address_space(3))) void*)l, 16, 0, 0);
}

// ---- CSR build: histogram (all 3 matrices, multi-block) ----
__global__ void hist_kernel(const int* __restrict__ rows0, const int* __restrict__ rows1,
                            const int* __restrict__ rows2, int* __restrict__ cur) {
    int e = blockIdx.x * NT + threadIdx.x;          // 0 .. 3*NNZ
    int m = e >> 14, i = e & (NNZc - 1);
    const int* rp = (m == 0) ? rows0 : (m == 1) ? rows1 : rows2;
    atomicAdd(&cur[m * DIM + rp[i]], 1);
}

// ---- CSR build: exclusive scan of 2048 counts (one block per matrix) ----
__global__ void scan_kernel(int* __restrict__ curb, int* __restrict__ offb) {
    int* cur = curb + blockIdx.x * DIM;
    int* off = offb + blockIdx.x * 2052;
    __shared__ int part[NT];
    int t = threadIdx.x;
    int c[8]; int s = 0;
    #pragma unroll
    for (int i = 0; i < 8; ++i) { c[i] = cur[t * 8 + i]; s += c[i]; }
    part[t] = s;
    __syncthreads();
    if (t == 0) {
        int run = 0;
        for (int i = 0; i < NT; ++i) { int v = part[i]; part[i] = run; run += v; }
    }
    __syncthreads();
    int base = part[t];
    #pragma unroll
    for (int i = 0; i < 8; ++i) {
        int idx = t * 8 + i;
        off[idx] = base; cur[idx] = base; base += c[i];
    }
    if (t == 0) off[DIM] = NNZc;
}

// ---- CSR build: scatter entries into row buckets ----
__global__ void scatter_kernel(const int* __restrict__ rows0, const int* __restrict__ cols0,
                               const float* __restrict__ vals0,
                               const int* __restrict__ rows1, const int* __restrict__ cols1,
                               const float* __restrict__ vals1,
                               const int* __restrict__ rows2, const int* __restrict__ cols2,
                               const float* __restrict__ vals2,
                               int* __restrict__ cur,
                               int* __restrict__ colb, float* __restrict__ valb) {
    int e = blockIdx.x * NT + threadIdx.x;
    int m = e >> 14, i = e & (NNZc - 1);
    const int*   rp = (m == 0) ? rows0 : (m == 1) ? rows1 : rows2;
    const int*   cp = (m == 0) ? cols0 : (m == 1) ? cols1 : cols2;
    const float* vp = (m == 0) ? vals0 : (m == 1) ? vals1 : vals2;
    int slot = atomicAdd(&cur[m * DIM + rp[i]], 1);
    colb[m * NNZc + slot] = cp[i];
    valb[m * NNZc + slot] = vp[i];
}

// ---- Mc build: per block, RPB output rows via 3-level tree walk in LDS ----
#define RPB  2
#define PCAP 2048
__global__ __launch_bounds__(NT) void mcbuild_kernel(
        const int* __restrict__ offb, const int* __restrict__ colb,
        const float* __restrict__ valb, unsigned short* __restrict__ Mc) {
    const int* off0 = offb;              const int* off1 = offb + 2052;  const int* off2 = offb + 4104;
    const int* col0 = colb;              const int* col1 = colb + NNZc;  const int* col2 = colb + 2 * NNZc;
    const float* val0 = valb;            const float* val1 = valb + NNZc; const float* val2 = valb + 2 * NNZc;

    __shared__ float acc[RPB * DIM];
    __shared__ int   pk[PCAP];
    __shared__ float pw[PCAP];
    __shared__ int   npairs;

    const int tid = threadIdx.x;
    const int r0  = blockIdx.x * RPB;

    f32x4* az = (f32x4*)acc;
    #pragma unroll
    for (int j = tid; j < RPB * DIM / 4; j += NT) az[j] = (f32x4){0.f, 0.f, 0.f, 0.f};
    if (tid == 0) npairs = 0;
    __syncthreads();

    #pragma unroll
    for (int k = 0; k < RPB; ++k) {
        int b = off0[r0 + k], e = off0[r0 + k + 1];
        for (int i = b + tid; i < e; i += NT) {
            int   c0 = col0[i];
            float v0 = val0[i];
            int b1 = off1[c0], e1 = off1[c0 + 1];
            for (int j = b1; j < e1; ++j) {
                float w = v0 * val1[j];
                int   c1 = col1[j];
                int slot = atomicAdd(&npairs, 1);
                if (slot < PCAP) { pk[slot] = (k << 16) | c1; pw[slot] = w; }
                else {
                    int b2 = off2[c1], e2 = off2[c1 + 1];
                    for (int q = b2; q < e2; ++q)
                        atomicAdd(&acc[k * DIM + col2[q]], w * val2[q]);
                }
            }
        }
    }
    __syncthreads();

    int np = min(npairs, PCAP);
    for (int p = tid; p < np; p += NT) {
        int   k  = pk[p] >> 16, c1 = pk[p] & 0xffff;
        float w  = pw[p];
        int b2 = off2[c1], e2 = off2[c1 + 1];
        for (int q = b2; q < e2; ++q)
            atomicAdd(&acc[k * DIM + col2[q]], w * val2[q]);
    }
    __syncthreads();

    #pragma unroll
    for (int k = 0; k < RPB; ++k) {
        unsigned short o[8];
        #pragma unroll
        for (int jj = 0; jj < 8; ++jj) o[jj] = f2bf(acc[k * DIM + tid * 8 + jj]);
        *(ulonglong2*)(Mc + (size_t)(r0 + k) * DIM + tid * 8) = *(ulonglong2*)o;
    }
}

// ---- x (f32) -> bf16 ----
__global__ void xconv_kernel(const float* __restrict__ x, unsigned short* __restrict__ Xb) {
    size_t i = ((size_t)blockIdx.x * NT + threadIdx.x) * 8;
    float4 a = *(const float4*)(x + i);
    float4 b = *(const float4*)(x + i + 4);
    unsigned short o[8] = {f2bf(a.x), f2bf(a.y), f2bf(a.z), f2bf(a.w),
                           f2bf(b.x), f2bf(b.y), f2bf(b.z), f2bf(b.w)};
    *(ulonglong2*)(Xb + i) = *(ulonglong2*)o;
}

// ---- GEMM: C = Xb(4096x2048) @ Mc^T + bias ----
// A-frags loaded DIRECTLY from global per lane (row=l&15, k-chunk=l>>4);
// B staged into 4-slot LDS ring (16 KiB/slot), involution swizzle
// phys_chunk = logical ^ ((row>>1)&3). Per step: 4 A gloads + 2 B stage
// gloads + 4 B ds_reads + 16 MFMA per wave. vmcnt(2) keeps B(s+3) in flight.
#define BM 128
#define BN 256
#define BK 32
#define NS (DIM / BK)            // 64
#define B_SL (BN * BK * 2)       // 16384 bytes per slot
#define GEMM_LDS (4 * B_SL)      // 65536

__global__ __launch_bounds__(512, 2) void gemm8(
        const unsigned short* __restrict__ A,   // Xb [4096][2048]
        const unsigned short* __restrict__ Bm,  // Mc [2048][2048]
        const float* __restrict__ bias,
        float* __restrict__ C) {
    extern __shared__ char smem[];
    const int tid = threadIdx.x;
    const int l = tid & 63, w = tid >> 6;
    const int wm = w & 1, wn = w >> 1;          // 2 x 4 wave grid, wave tile 64x64
    const int tileM = blockIdx.y * BM;
    const int tileN = blockIdx.x * BN;

    // ---- B staging: thread (w,l) covers B row 32w + (l>>2), phys chunk l&3 ----
    const int lr = l >> 2;
    const int lc = (l & 3) ^ ((l >> 3) & 3);        // logical chunk pre-swizzled
    const unsigned short* bSrc0 = Bm + (size_t)(tileN + 32 * w + lr) * DIM + lc * 8;
    const unsigned short* bSrc1 = bSrc0 + (size_t)16 * DIM;

#define STAGEB(zbase, s) do {                                      \
    gload16(bSrc0 + (size_t)(s) * BK, (zbase) + w * 2048);         \
    gload16(bSrc1 + (size_t)(s) * BK, (zbase) + w * 2048 + 1024);  \
} while (0)

    // ---- A direct-from-global: lane l reads row (l&15), k-chunk (l>>4) ----
    const unsigned short* aP = A + (size_t)(tileM + wm * 64 + (l & 15)) * DIM + (l >> 4) * 8;

#define LOADA(Af, s) do {                                              \
    Af[0] = *(const bf16x8*)(aP +            (size_t)(s) * BK);        \
    Af[1] = *(const bf16x8*)(aP + 16 * DIM + (size_t)(s) * BK);        \
    Af[2] = *(const bf16x8*)(aP + 32 * DIM + (size_t)(s) * BK);        \
    Af[3] = *(const bf16x8*)(aP + 48 * DIM + (size_t)(s) * BK);        \
} while (0)

    // ---- B LDS frag reads: row = wn*64 + j*16 + (l&15), swizzled chunk ----
    const int brow = (wn * 64 + (l & 15)) * 64 + (((l >> 4) ^ ((l >> 1) & 3)) * 16);

#define LOADB(zbase, Bf) do {                    \
    const char* _bb = (zbase) + brow;            \
    Bf[0] = *(const bf16x8*)(_bb);               \
    Bf[1] = *(const bf16x8*)(_bb + 1024);        \
    Bf[2] = *(const bf16x8*)(_bb + 2048);        \
    Bf[3] = *(const bf16x8*)(_bb + 3072);        \
} while (0)

#define MFMA16(Af, Bf) do {                                                            \
    _Pragma("unroll")                                                                  \
    for (int _q = 0; _q < 4; ++_q)                                                     \
        _Pragma("unroll")                                                              \
        for (int _j = 0; _j < 4; ++_j)                                                 \
            acc[_q][_j] = __builtin_amdgcn_mfma_f32_16x16x32_bf16(Af[_q], Bf[_j],      \
                                                                  acc[_q][_j], 0,0,0); \
} while (0)

#define ENDSTEP(vm) do {                                      \
    __builtin_amdgcn_sched_barrier(0);                        \
    asm volatile("s_waitcnt vmcnt(" #vm ")" ::: "memory");    \
    asm volatile("s_waitcnt lgkmcnt(0)" ::: "memory");        \
    __builtin_amdgcn_sched_barrier(0);                        \
    __builtin_amdgcn_s_barrier();                             \
} while (0)

    bf16x8 Ae[4], Be[4], Ao[4], Bo[4];
    f32x4 acc[4][4] = {};

    // ---- prologue: A(0) -> Ae; stage B slots 0,1,2; wait A0+B0+B1; read B0 ----
    LOADA(Ae, 0);
    __builtin_amdgcn_sched_barrier(0);
    STAGEB(smem, 0);
    STAGEB(smem + 1 * B_SL, 1);
    STAGEB(smem + 2 * B_SL, 2);
    __builtin_amdgcn_sched_barrier(0);
    asm volatile("s_waitcnt vmcnt(2)" ::: "memory");   // allow B(2) in flight
    __builtin_amdgcn_sched_barrier(0);
    __builtin_amdgcn_s_barrier();
    LOADB(smem, Be);

    // ---- main loop: steps 0..59 in even/odd pairs ----
    for (int t = 0; t < 30; ++t) {
        const int s = 2 * t;
        {   // even: A(s+1)->Ao, stage B(s+3), read B(s+1)->Bo, MFMA(Ae,Be)
            LOADA(Ao, s + 1);
            __builtin_amdgcn_sched_barrier(0);
            STAGEB(smem + ((s + 3) & 3) * B_SL, s + 3);
            LOADB(smem + ((s + 1) & 3) * B_SL, Bo);
            __builtin_amdgcn_sched_barrier(0);
            __builtin_amdgcn_s_setprio(1);
            MFMA16(Ae, Be);
            __builtin_amdgcn_s_setprio(0);
            ENDSTEP(2);
        }
        {   // odd: A(s+2)->Ae, stage B(s+4), read B(s+2)->Be, MFMA(Ao,Bo)
            LOADA(Ae, s + 2);
            __builtin_amdgcn_sched_barrier(0);
            STAGEB(smem + ((s + 4) & 3) * B_SL, s + 4);
            LOADB(smem + ((s + 2) & 3) * B_SL, Be);
            __builtin_amdgcn_sched_barrier(0);
            __builtin_amdgcn_s_setprio(1);
            MFMA16(Ao, Bo);
            __builtin_amdgcn_s_setprio(0);
            ENDSTEP(2);
        }
    }
    // ---- tail: steps 60..63 ----
    {   // s=60 (even): stage B(63) is the last stage
        LOADA(Ao, 61);
        __builtin_amdgcn_sched_barrier(0);
        STAGEB(smem + 3 * B_SL, 63);
        LOADB(smem + 1 * B_SL, Bo);
        __builtin_amdgcn_sched_barrier(0);
        __builtin_amdgcn_s_setprio(1);
        MFMA16(Ae, Be);
        __builtin_amdgcn_s_setprio(0);
        ENDSTEP(2);
    }
    {   // s=61 (odd): no staging; drain everything
        LOADA(Ae, 62);
        __builtin_amdgcn_sched_barrier(0);
        LOADB(smem + 2 * B_SL, Be);
        __builtin_amdgcn_sched_barrier(0);
        __builtin_amdgcn_s_setprio(1);
        MFMA16(Ao, Bo);
        __builtin_amdgcn_s_setprio(0);
        ENDSTEP(0);
    }
    {   // s=62 (even): last loads
        LOADA(Ao, 63);
        __builtin_amdgcn_sched_barrier(0);
        LOADB(smem + 3 * B_SL, Bo);
        __builtin_amdgcn_sched_barrier(0);
        __builtin_amdgcn_s_setprio(1);
        MFMA16(Ae, Be);
        __builtin_amdgcn_s_setprio(0);
        __builtin_amdgcn_sched_barrier(0);
        asm volatile("s_waitcnt vmcnt(0)" ::: "memory");
        asm volatile("s_waitcnt lgkmcnt(0)" ::: "memory");
        __builtin_amdgcn_sched_barrier(0);
    }
    // s=63
    MFMA16(Ao, Bo);

    // ---- epilogue: C = acc + bias ----
    #pragma unroll
    for (int j = 0; j < 4; ++j) {
        int col = tileN + wn * 64 + j * 16 + (l & 15);
        float bj = bias[col];
        #pragma unroll
        for (int i = 0; i < 4; ++i) {
            int rw = tileM + wm * 64 + i * 16 + (l >> 4) * 4;
            #pragma unroll
            for (int r = 0; r < 4; ++r)
                C[(size_t)(rw + r) * DIM + col] = acc[i][j][r] + bj;
        }
    }
}

extern "C" void kernel_launch(void* const* d_in, const int* in_sizes, int n_in,
                              void* d_out, int out_size, void* d_ws, size_t ws_size,
                              hipStream_t stream) {
    const float* x     = (const float*)d_in[0];
    const int*   rows0 = (const int*)  d_in[1];
    const int*   cols0 = (const int*)  d_in[2];
    const float* vals0 = (const float*)d_in[3];
    const int*   rows1 = (const int*)  d_in[4];
    const int*   cols1 = (const int*)  d_in[5];
    const float* vals1 = (const float*)d_in[6];
    const int*   rows2 = (const int*)  d_in[7];
    const int*   cols2 = (const int*)  d_in[8];
    const float* vals2 = (const float*)d_in[9];
    const float* bias  = (const float*)d_in[10];
    float* out = (float*)d_out;

    char* ws = (char*)d_ws;
    unsigned short* Mc = (unsigned short*)ws;                 // 8 MB
    unsigned short* Xb = (unsigned short*)(ws + 8388608);     // 16 MB
    int*   offb = (int*)(ws + 25165824);      // 3 * 2052
    int*   curb = offb + 3 * 2052;            // 3 * 2048
    int*   colb = curb + 3 * DIM;             // 3 * 16384
    float* valb = (float*)(colb + 3 * NNZc);  // 3 * 16384

    hipMemsetAsync(curb, 0, 3 * DIM * sizeof(int), stream);

    hist_kernel<<<3 * NNZc / NT, NT, 0, stream>>>(rows0, rows1, rows2, curb);
    scan_kernel<<<3, NT, 0, stream>>>(curb, offb);
    scatter_kernel<<<3 * NNZc / NT, NT, 0, stream>>>(rows0, cols0, vals0,
                                                     rows1, cols1, vals1,
                                                     rows2, cols2, vals2,
                                                     curb, colb, valb);
    mcbuild_kernel<<<DIM / RPB, NT, 0, stream>>>(offb, colb, valb, Mc);
    xconv_kernel<<<(BATCH * DIM) / (NT * 8), NT, 0, stream>>>(x, Xb);

    (void)hipFuncSetAttribute((const void*)gemm8,
                              hipFuncAttributeMaxDynamicSharedMemorySize, GEMM_LDS);
    dim3 ggrid(DIM / BN, BATCH / BM);   // 8 x 32 = 256 blocks
    gemm8<<<ggrid, 512, GEMM_LDS, stream>>>(Xb, Mc, bias, out);
}

// Round 9
// 104.503 us; speedup vs baseline: 1.2631x; 1.2631x over previous
//
#include <hip/hip_runtime.h>

// SparseProductLayer:  out = x @ (M0*M1*M2)^T + bias
// Pipeline: multi-block CSR build -> entry-wise Mc build -> x->bf16 in MFMA
// FRAGMENT layout (XbF) -> MFMA GEMM: A-frags coalesced direct-from-global
// (L1-served), B through 4-slot LDS ring, counted vmcnt, involution swizzle.
// BM=128,BN=256,BK=32, 8 waves (2x4), 256 blocks = 1/CU.
//
// XbF layout: XbF[rg][s][l][j] = Xb[rg*16+(l&15)][s*32+(l>>4)*8+j]
//   rg in [0,256), s in [0,64), l in [0,64), j in [0,8). 16 MB.
//
// d_ws layout (bytes):
//   [0)         Mc  bf16 [D][D]     8388608
//   [8388608)   XbF bf16 frag      16777216
//   [25165824)  CSR: off[3][2052], cur[3][2048], col[3][16384], val[3][16384]

#define BATCH 4096
#define DIM   2048
#define NNZc  16384
#define NT    256

typedef short bf16x8 __attribute__((ext_vector_type(8)));
typedef float f32x4  __attribute__((ext_vector_type(4)));

__device__ __forceinline__ unsigned short f2bf(float f) {
    unsigned u = __float_as_uint(f);
    unsigned r = (u + 0x7fffu + ((u >> 16) & 1u)) >> 16;   // RNE
    return (unsigned short)r;
}

__device__ __forceinline__ void gload16(const void* g, void* l) {
    __builtin_amdgcn_global_load_lds((const __attribute__((address_space(1))) void*)g,
                                     (__attribute__((address_space(3))) void*)l, 16, 0, 0);
}

// ---- CSR build: histogram (all 3 matrices, multi-block) ----
__global__ void hist_kernel(const int* __restrict__ rows0, const int* __restrict__ rows1,
                            const int* __restrict__ rows2, int* __restrict__ cur) {
    int e = blockIdx.x * NT + threadIdx.x;          // 0 .. 3*NNZ
    int m = e >> 14, i = e & (NNZc - 1);
    const int* rp = (m == 0) ? rows0 : (m == 1) ? rows1 : rows2;
    atomicAdd(&cur[m * DIM + rp[i]], 1);
}

// ---- CSR build: exclusive scan of 2048 counts (parallel shuffle scan) ----
__global__ void scan_kernel(int* __restrict__ curb, int* __restrict__ offb) {
    int* cur = curb + blockIdx.x * DIM;
    int* off = offb + blockIdx.x * 2052;
    __shared__ int wsum[4];
    int t = threadIdx.x;
    int c[8]; int s = 0;
    #pragma unroll
    for (int i = 0; i < 8; ++i) { c[i] = cur[t * 8 + i]; s += c[i]; }
    int l = t & 63, wv = t >> 6;
    int v = s;
    #pragma unroll
    for (int d = 1; d < 64; d <<= 1) {
        int u = __shfl_up(v, d, 64);
        if (l >= d) v += u;
    }
    if (l == 63) wsum[wv] = v;
    __syncthreads();
    int wbase = 0;
    for (int i = 0; i < wv; ++i) wbase += wsum[i];
    int base = wbase + v - s;     // exclusive prefix for this thread's 8 bins
    #pragma unroll
    for (int i = 0; i < 8; ++i) {
        int idx = t * 8 + i;
        off[idx] = base; cur[idx] = base; base += c[i];
    }
    if (t == 0) off[DIM] = NNZc;
}

// ---- CSR build: scatter entries into row buckets ----
__global__ void scatter_kernel(const int* __restrict__ rows0, const int* __restrict__ cols0,
                               const float* __restrict__ vals0,
                               const int* __restrict__ rows1, const int* __restrict__ cols1,
                               const float* __restrict__ vals1,
                               const int* __restrict__ rows2, const int* __restrict__ cols2,
                               const float* __restrict__ vals2,
                               int* __restrict__ cur,
                               int* __restrict__ colb, float* __restrict__ valb) {
    int e = blockIdx.x * NT + threadIdx.x;
    int m = e >> 14, i = e & (NNZc - 1);
    const int*   rp = (m == 0) ? rows0 : (m == 1) ? rows1 : rows2;
    const int*   cp = (m == 0) ? cols0 : (m == 1) ? cols1 : cols2;
    const float* vp = (m == 0) ? vals0 : (m == 1) ? vals1 : vals2;
    int slot = atomicAdd(&cur[m * DIM + rp[i]], 1);
    colb[m * NNZc + slot] = cp[i];
    valb[m * NNZc + slot] = vp[i];
}

// ---- Mc build: per block, RPB output rows via 3-level tree walk in LDS ----
#define RPB  2
#define PCAP 2048
__global__ __launch_bounds__(NT) void mcbuild_kernel(
        const int* __restrict__ offb, const int* __restrict__ colb,
        const float* __restrict__ valb, unsigned short* __restrict__ Mc) {
    const int* off0 = offb;              const int* off1 = offb + 2052;  const int* off2 = offb + 4104;
    const int* col0 = colb;              const int* col1 = colb + NNZc;  const int* col2 = colb + 2 * NNZc;
    const float* val0 = valb;            const float* val1 = valb + NNZc; const float* val2 = valb + 2 * NNZc;

    __shared__ float acc[RPB * DIM];
    __shared__ int   pk[PCAP];
    __shared__ float pw[PCAP];
    __shared__ int   npairs;

    const int tid = threadIdx.x;
    const int r0  = blockIdx.x * RPB;

    f32x4* az = (f32x4*)acc;
    #pragma unroll
    for (int j = tid; j < RPB * DIM / 4; j += NT) az[j] = (f32x4){0.f, 0.f, 0.f, 0.f};
    if (tid == 0) npairs = 0;
    __syncthreads();

    #pragma unroll
    for (int k = 0; k < RPB; ++k) {
        int b = off0[r0 + k], e = off0[r0 + k + 1];
        for (int i = b + tid; i < e; i += NT) {
            int   c0 = col0[i];
            float v0 = val0[i];
            int b1 = off1[c0], e1 = off1[c0 + 1];
            for (int j = b1; j < e1; ++j) {
                float w = v0 * val1[j];
                int   c1 = col1[j];
                int slot = atomicAdd(&npairs, 1);
                if (slot < PCAP) { pk[slot] = (k << 16) | c1; pw[slot] = w; }
                else {
                    int b2 = off2[c1], e2 = off2[c1 + 1];
                    for (int q = b2; q < e2; ++q)
                        atomicAdd(&acc[k * DIM + col2[q]], w * val2[q]);
                }
            }
        }
    }
    __syncthreads();

    int np = min(npairs, PCAP);
    for (int p = tid; p < np; p += NT) {
        int   k  = pk[p] >> 16, c1 = pk[p] & 0xffff;
        float w  = pw[p];
        int b2 = off2[c1], e2 = off2[c1 + 1];
        for (int q = b2; q < e2; ++q)
            atomicAdd(&acc[k * DIM + col2[q]], w * val2[q]);
    }
    __syncthreads();

    #pragma unroll
    for (int k = 0; k < RPB; ++k) {
        unsigned short o[8];
        #pragma unroll
        for (int jj = 0; jj < 8; ++jj) o[jj] = f2bf(acc[k * DIM + tid * 8 + jj]);
        *(ulonglong2*)(Mc + (size_t)(r0 + k) * DIM + tid * 8) = *(ulonglong2*)o;
    }
}

// ---- x (f32) -> bf16, written in MFMA fragment layout XbF ----
__global__ void xconv_kernel(const float* __restrict__ x, unsigned short* __restrict__ XbF) {
    int g  = blockIdx.x * NT + threadIdx.x;
    int b  = g >> 8;             // row, 0..4095 (wave-contiguous source reads)
    int d0 = (g & 255) * 8;      // col base
    float4 a = *(const float4*)(x + (size_t)b * DIM + d0);
    float4 c = *(const float4*)(x + (size_t)b * DIM + d0 + 4);
    unsigned short o[8] = {f2bf(a.x), f2bf(a.y), f2bf(a.z), f2bf(a.w),
                           f2bf(c.x), f2bf(c.y), f2bf(c.z), f2bf(c.w)};
    int rg = b >> 4;
    int s  = d0 >> 5;
    int l  = (b & 15) | (((d0 >> 3) & 3) << 4);
    *(ulonglong2*)(XbF + ((((size_t)rg * 64) + s) * 64 + l) * 8) = *(ulonglong2*)o;
}

// ---- GEMM: C = Xb(4096x2048) @ Mc^T + bias ----
// A-frags: ONE coalesced global_load_dwordx4 each from XbF (L1-served,
// 4-way reuse across wn-waves), pipelined 1 step ahead. B: 4-slot LDS ring,
// involution swizzle phys_chunk = logical ^ ((row>>1)&3), staged 3 ahead.
// Per step/wave: 4 A gloads + 2 B stage gloads + 4 B ds_reads + 16 MFMA.
#define BM 128
#define BN 256
#define BK 32
#define NS (DIM / BK)            // 64
#define B_SL (BN * BK * 2)       // 16384 bytes per slot
#define GEMM_LDS (4 * B_SL)      // 65536

__global__ __launch_bounds__(512, 2) void gemm8(
        const unsigned short* __restrict__ XbF,  // frag-layout A
        const unsigned short* __restrict__ Bm,   // Mc [2048][2048]
        const float* __restrict__ bias,
        float* __restrict__ C) {
    extern __shared__ char smem[];
    const int tid = threadIdx.x;
    const int l = tid & 63, w = tid >> 6;
    const int wm = w & 1, wn = w >> 1;          // 2 x 4 wave grid, wave tile 64x64
    const int tileM = blockIdx.y * BM;
    const int tileN = blockIdx.x * BN;

    // ---- B staging: thread (w,l) covers B row 32w + (l>>2), phys chunk l&3 ----
    const int lr = l >> 2;
    const int lc = (l & 3) ^ ((l >> 3) & 3);        // logical chunk pre-swizzled
    const unsigned short* bSrc0 = Bm + (size_t)(tileN + 32 * w + lr) * DIM + lc * 8;
    const unsigned short* bSrc1 = bSrc0 + (size_t)16 * DIM;

#define STAGEB(zbase, s) do {                                      \
    gload16(bSrc0 + (size_t)(s) * BK, (zbase) + w * 2048);         \
    gload16(bSrc1 + (size_t)(s) * BK, (zbase) + w * 2048 + 1024);  \
} while (0)

    // ---- A frag base: frag q, step s at aBase + q*32768 + s*512 (shorts) ----
    const unsigned short* aBase =
        XbF + ((size_t)((tileM >> 4) + wm * 4) * 64) * 64 * 8 + l * 8;

#define LOADA(Af, s) do {                                                  \
    Af[0] = *(const bf16x8*)(aBase + 0 * 32768 + (size_t)(s) * 512);       \
    Af[1] = *(const bf16x8*)(aBase + 1 * 32768 + (size_t)(s) * 512);       \
    Af[2] = *(const bf16x8*)(aBase + 2 * 32768 + (size_t)(s) * 512);       \
    Af[3] = *(const bf16x8*)(aBase + 3 * 32768 + (size_t)(s) * 512);       \
} while (0)

    // ---- B LDS frag reads: row = wn*64 + j*16 + (l&15), swizzled chunk ----
    const int brow = (wn * 64 + (l & 15)) * 64 + (((l >> 4) ^ ((l >> 1) & 3)) * 16);

#define LOADB(zbase, Bf) do {                    \
    const char* _bb = (zbase) + brow;            \
    Bf[0] = *(const bf16x8*)(_bb);               \
    Bf[1] = *(const bf16x8*)(_bb + 1024);        \
    Bf[2] = *(const bf16x8*)(_bb + 2048);        \
    Bf[3] = *(const bf16x8*)(_bb + 3072);        \
} while (0)

#define MFMA16(Af, Bf) do {                                                            \
    _Pragma("unroll")                                                                  \
    for (int _q = 0; _q < 4; ++_q)                                                     \
        _Pragma("unroll")                                                              \
        for (int _j = 0; _j < 4; ++_j)                                                 \
            acc[_q][_j] = __builtin_amdgcn_mfma_f32_16x16x32_bf16(Af[_q], Bf[_j],      \
                                                                  acc[_q][_j], 0,0,0); \
} while (0)

#define ENDSTEP(vm) do {                                      \
    __builtin_amdgcn_sched_barrier(0);                        \
    asm volatile("s_waitcnt vmcnt(" #vm ")" ::: "memory");    \
    asm volatile("s_waitcnt lgkmcnt(0)" ::: "memory");        \
    __builtin_amdgcn_sched_barrier(0);                        \
    __builtin_amdgcn_s_barrier();                             \
} while (0)

    bf16x8 Ae[4], Be[4], Ao[4], Bo[4];
    f32x4 acc[4][4] = {};

    // ---- prologue: A(0); stage B slots 0,1,2; wait A0+B0; read B0 ----
    LOADA(Ae, 0);
    __builtin_amdgcn_sched_barrier(0);
    STAGEB(smem, 0);
    STAGEB(smem + 1 * B_SL, 1);
    STAGEB(smem + 2 * B_SL, 2);
    __builtin_amdgcn_sched_barrier(0);
    asm volatile("s_waitcnt vmcnt(4)" ::: "memory");   // A0+B0 done; B1,B2 in flight
    __builtin_amdgcn_sched_barrier(0);
    __builtin_amdgcn_s_barrier();
    LOADB(smem, Be);

    // ---- main loop: steps 0..59 in even/odd pairs ----
    for (int t = 0; t < 30; ++t) {
        const int s = 2 * t;
        {   // even: A(s+1)->Ao, stage B(s+3), read B(s+1)->Bo, MFMA(Ae,Be)
            LOADA(Ao, s + 1);
            __builtin_amdgcn_sched_barrier(0);
            STAGEB(smem + ((s + 3) & 3) * B_SL, s + 3);
            LOADB(smem + ((s + 1) & 3) * B_SL, Bo);
            __builtin_amdgcn_sched_barrier(0);
            __builtin_amdgcn_s_setprio(1);
            MFMA16(Ae, Be);
            __builtin_amdgcn_s_setprio(0);
            ENDSTEP(2);
        }
        {   // odd: A(s+2)->Ae, stage B(s+4), read B(s+2)->Be, MFMA(Ao,Bo)
            LOADA(Ae, s + 2);
            __builtin_amdgcn_sched_barrier(0);
            STAGEB(smem + ((s + 4) & 3) * B_SL, s + 4);
            LOADB(smem + ((s + 2) & 3) * B_SL, Be);
            __builtin_amdgcn_sched_barrier(0);
            __builtin_amdgcn_s_setprio(1);
            MFMA16(Ao, Bo);
            __builtin_amdgcn_s_setprio(0);
            ENDSTEP(2);
        }
    }
    // ---- tail: steps 60..63 ----
    {   // s=60: stage B(63) is the last stage
        LOADA(Ao, 61);
        __builtin_amdgcn_sched_barrier(0);
        STAGEB(smem + 3 * B_SL, 63);
        LOADB(smem + 1 * B_SL, Bo);
        __builtin_amdgcn_sched_barrier(0);
        __builtin_amdgcn_s_setprio(1);
        MFMA16(Ae, Be);
        __builtin_amdgcn_s_setprio(0);
        ENDSTEP(2);
    }
    {   // s=61: drain everything (B63 + A62)
        LOADA(Ae, 62);
        __builtin_amdgcn_sched_barrier(0);
        LOADB(smem + 2 * B_SL, Be);
        __builtin_amdgcn_sched_barrier(0);
        __builtin_amdgcn_s_setprio(1);
        MFMA16(Ao, Bo);
        __builtin_amdgcn_s_setprio(0);
        ENDSTEP(0);
    }
    {   // s=62: last A load; no barrier needed after
        LOADA(Ao, 63);
        __builtin_amdgcn_sched_barrier(0);
        LOADB(smem + 3 * B_SL, Bo);
        __builtin_amdgcn_sched_barrier(0);
        __builtin_amdgcn_s_setprio(1);
        MFMA16(Ae, Be);
        __builtin_amdgcn_s_setprio(0);
        __builtin_amdgcn_sched_barrier(0);
        asm volatile("s_waitcnt vmcnt(0)" ::: "memory");
        asm volatile("s_waitcnt lgkmcnt(0)" ::: "memory");
        __builtin_amdgcn_sched_barrier(0);
    }
    // s=63
    MFMA16(Ao, Bo);

    // ---- epilogue: C = acc + bias ----
    #pragma unroll
    for (int j = 0; j < 4; ++j) {
        int col = tileN + wn * 64 + j * 16 + (l & 15);
        float bj = bias[col];
        #pragma unroll
        for (int i = 0; i < 4; ++i) {
            int rw = tileM + wm * 64 + i * 16 + (l >> 4) * 4;
            #pragma unroll
            for (int r = 0; r < 4; ++r)
                C[(size_t)(rw + r) * DIM + col] = acc[i][j][r] + bj;
        }
    }
}

extern "C" void kernel_launch(void* const* d_in, const int* in_sizes, int n_in,
                              void* d_out, int out_size, void* d_ws, size_t ws_size,
                              hipStream_t stream) {
    const float* x     = (const float*)d_in[0];
    const int*   rows0 = (const int*)  d_in[1];
    const int*   cols0 = (const int*)  d_in[2];
    const float* vals0 = (const float*)d_in[3];
    const int*   rows1 = (const int*)  d_in[4];
    const int*   cols1 = (const int*)  d_in[5];
    const float* vals1 = (const float*)d_in[6];
    const int*   rows2 = (const int*)  d_in[7];
    const int*   cols2 = (const int*)  d_in[8];
    const float* vals2 = (const float*)d_in[9];
    const float* bias  = (const float*)d_in[10];
    float* out = (float*)d_out;

    char* ws = (char*)d_ws;
    unsigned short* Mc  = (unsigned short*)ws;                 // 8 MB
    unsigned short* XbF = (unsigned short*)(ws + 8388608);     // 16 MB
    int*   offb = (int*)(ws + 25165824);      // 3 * 2052
    int*   curb = offb + 3 * 2052;            // 3 * 2048
    int*   colb = curb + 3 * DIM;             // 3 * 16384
    float* valb = (float*)(colb + 3 * NNZc);  // 3 * 16384

    hipMemsetAsync(curb, 0, 3 * DIM * sizeof(int), stream);

    hist_kernel<<<3 * NNZc / NT, NT, 0, stream>>>(rows0, rows1, rows2, curb);
    scan_kernel<<<3, NT, 0, stream>>>(curb, offb);
    scatter_kernel<<<3 * NNZc / NT, NT, 0, stream>>>(rows0, cols0, vals0,
                                                     rows1, cols1, vals1,
                                                     rows2, cols2, vals2,
                                                     curb, colb, valb);
    mcbuild_kernel<<<DIM / RPB, NT, 0, stream>>>(offb, colb, valb, Mc);
    xconv_kernel<<<(BATCH * DIM) / (NT * 8), NT, 0, stream>>>(x, XbF);

    (void)hipFuncSetAttribute((const void*)gemm8,
                              hipFuncAttributeMaxDynamicSharedMemorySize, GEMM_LDS);
    dim3 ggrid(DIM / BN, BATCH / BM);   // 8 x 32 = 256 blocks
    gemm8<<<ggrid, 512, GEMM_LDS, stream>>>(XbF, Mc, bias, out);
}

// Round 10
// 98.763 us; speedup vs baseline: 1.3365x; 1.0581x over previous
//
#include <hip/hip_runtime.h>

// SparseProductLayer:  out = x @ (M0*M1*M2)^T + bias
// Pipeline: fused 3-block CSR build -> entry-wise Mc build -> x->bf16 (linear)
// -> MFMA GEMM: BM=128,BN=256,BK=64, 3-slot LDS ring (144 KB), ONE barrier
// per K-step, counted vmcnt(6) w/ full-step latency cover, pinned frag
// double-buffer (reads s+1 overlap MFMA s), chunk^row&7 swizzle, setprio.
// 256 blocks = 1/CU.
//
// d_ws layout (bytes):
//   [0)         Mc  bf16 [D][D]     8388608
//   [8388608)   Xb  bf16 [B][D]    16777216
//   [25165824)  CSR: off[3][2052], col[3][16384], val[3][16384]

#define BATCH 4096
#define DIM   2048
#define NNZc  16384
#define NT    256

typedef short bf16x8 __attribute__((ext_vector_type(8)));
typedef float f32x4  __attribute__((ext_vector_type(4)));

__device__ __forceinline__ unsigned short f2bf(float f) {
    unsigned u = __float_as_uint(f);
    unsigned r = (u + 0x7fffu + ((u >> 16) & 1u)) >> 16;   // RNE
    return (unsigned short)r;
}

__device__ __forceinline__ void gload16(const void* g, void* l) {
    __builtin_amdgcn_global_load_lds((const __attribute__((address_space(1))) void*)g,
                                     (__attribute__((address_space(3))) void*)l, 16, 0, 0);
}

// ---- fused CSR build: one block per matrix (hist + shuffle-scan + scatter) ----
__global__ __launch_bounds__(1024) void csr3_kernel(
        const int* __restrict__ r0, const int* __restrict__ c0, const float* __restrict__ v0,
        const int* __restrict__ r1, const int* __restrict__ c1, const float* __restrict__ v1,
        const int* __restrict__ r2, const int* __restrict__ c2, const float* __restrict__ v2,
        int* __restrict__ offb, int* __restrict__ colb, float* __restrict__ valb) {
    const int m = blockIdx.x;
    const int*   rows = (m == 0) ? r0 : (m == 1) ? r1 : r2;
    const int*   cols = (m == 0) ? c0 : (m == 1) ? c1 : c2;
    const float* vals = (m == 0) ? v0 : (m == 1) ? v1 : v2;

    __shared__ int cnt[2048];
    __shared__ int wsum[16];
    const int t = threadIdx.x;
    cnt[t] = 0; cnt[t + 1024] = 0;
    __syncthreads();
    for (int e = t; e < NNZc; e += 1024) atomicAdd(&cnt[rows[e]], 1);
    __syncthreads();
    int ca = cnt[2 * t], cb = cnt[2 * t + 1], s = ca + cb;
    int lane = t & 63, wv = t >> 6;
    int v = s;
    #pragma unroll
    for (int d = 1; d < 64; d <<= 1) {
        int u = __shfl_up(v, d, 64);
        if (lane >= d) v += u;
    }
    if (lane == 63) wsum[wv] = v;
    __syncthreads();
    int wbase = 0;
    for (int i = 0; i < wv; ++i) wbase += wsum[i];
    int base = wbase + v - s;                     // exclusive prefix
    offb[m * 2052 + 2 * t]     = base;
    offb[m * 2052 + 2 * t + 1] = base + ca;
    cnt[2 * t]     = base;
    cnt[2 * t + 1] = base + ca;
    if (t == 0) offb[m * 2052 + 2048] = NNZc;
    __syncthreads();
    for (int e = t; e < NNZc; e += 1024) {
        int slot = atomicAdd(&cnt[rows[e]], 1);
        colb[m * NNZc + slot] = cols[e];
        valb[m * NNZc + slot] = vals[e];
    }
}

// ---- Mc build: per block, RPB output rows via 3-level tree walk in LDS ----
#define RPB  2
#define PCAP 2048
__global__ __launch_bounds__(NT) void mcbuild_kernel(
        const int* __restrict__ offb, const int* __restrict__ colb,
        const float* __restrict__ valb, unsigned short* __restrict__ Mc) {
    const int* off0 = offb;              const int* off1 = offb + 2052;  const int* off2 = offb + 4104;
    const int* col0 = colb;              const int* col1 = colb + NNZc;  const int* col2 = colb + 2 * NNZc;
    const float* val0 = valb;            const float* val1 = valb + NNZc; const float* val2 = valb + 2 * NNZc;

    __shared__ float acc[RPB * DIM];
    __shared__ int   pk[PCAP];
    __shared__ float pw[PCAP];
    __shared__ int   npairs;

    const int tid = threadIdx.x;
    const int r0  = blockIdx.x * RPB;

    f32x4* az = (f32x4*)acc;
    #pragma unroll
    for (int j = tid; j < RPB * DIM / 4; j += NT) az[j] = (f32x4){0.f, 0.f, 0.f, 0.f};
    if (tid == 0) npairs = 0;
    __syncthreads();

    #pragma unroll
    for (int k = 0; k < RPB; ++k) {
        int b = off0[r0 + k], e = off0[r0 + k + 1];
        for (int i = b + tid; i < e; i += NT) {
            int   c0 = col0[i];
            float v0 = val0[i];
            int b1 = off1[c0], e1 = off1[c0 + 1];
            for (int j = b1; j < e1; ++j) {
                float w = v0 * val1[j];
                int   c1 = col1[j];
                int slot = atomicAdd(&npairs, 1);
                if (slot < PCAP) { pk[slot] = (k << 16) | c1; pw[slot] = w; }
                else {
                    int b2 = off2[c1], e2 = off2[c1 + 1];
                    for (int q = b2; q < e2; ++q)
                        atomicAdd(&acc[k * DIM + col2[q]], w * val2[q]);
                }
            }
        }
    }
    __syncthreads();

    int np = min(npairs, PCAP);
    for (int p = tid; p < np; p += NT) {
        int   k  = pk[p] >> 16, c1 = pk[p] & 0xffff;
        float w  = pw[p];
        int b2 = off2[c1], e2 = off2[c1 + 1];
        for (int q = b2; q < e2; ++q)
            atomicAdd(&acc[k * DIM + col2[q]], w * val2[q]);
    }
    __syncthreads();

    #pragma unroll
    for (int k = 0; k < RPB; ++k) {
        unsigned short o[8];
        #pragma unroll
        for (int jj = 0; jj < 8; ++jj) o[jj] = f2bf(acc[k * DIM + tid * 8 + jj]);
        *(ulonglong2*)(Mc + (size_t)(r0 + k) * DIM + tid * 8) = *(ulonglong2*)o;
    }
}

// ---- x (f32) -> bf16, linear layout ----
__global__ void xconv_kernel(const float* __restrict__ x, unsigned short* __restrict__ Xb) {
    size_t i = ((size_t)blockIdx.x * NT + threadIdx.x) * 8;
    float4 a = *(const float4*)(x + i);
    float4 b = *(const float4*)(x + i + 4);
    unsigned short o[8] = {f2bf(a.x), f2bf(a.y), f2bf(a.z), f2bf(a.w),
                           f2bf(b.x), f2bf(b.y), f2bf(b.z), f2bf(b.w)};
    *(ulonglong2*)(Xb + i) = *(ulonglong2*)o;
}

// ---- GEMM: C = Xb(4096x2048) @ Mc^T + bias ----
// 3-slot ring, BK=64. LDS slot: A [128 rows][64 k] (128-B rows, 16 KB) then
// B [256][64] (32 KB). Swizzle: phys 16B-chunk = logical ^ (row&7).
// Per step/wave: 6 gload_lds (stage s+2) + 16 ds_read_b128 (frags s+1,
// pinned, overlap MFMA s) + 32 MFMA. One barrier/step, vmcnt(6).
#define BM 128
#define BN 256
#define BK 64
#define NS (DIM / BK)                   // 32
#define A_SL (BM * BK * 2)              // 16384
#define B_SL (BN * BK * 2)              // 32768
#define SLOT (A_SL + B_SL)              // 49152
#define GEMM_LDS (3 * SLOT)             // 147456

__global__ __launch_bounds__(512, 2) void gemm8(
        const unsigned short* __restrict__ A,   // Xb [4096][2048]
        const unsigned short* __restrict__ Bm,  // Mc [2048][2048]
        const float* __restrict__ bias,
        float* __restrict__ C) {
    extern __shared__ char smem[];
    const int tid = threadIdx.x;
    const int l = tid & 63, w = tid >> 6;
    const int wm = w & 1, wn = w >> 1;          // 2M x 4N wave grid, tile 64x64
    const int tileM = blockIdx.y * BM;
    const int tileN = blockIdx.x * BN;

    // ---- staging: lane l covers row-in-8 (l>>3), phys chunk l&7 ----
    const int r8   = l >> 3;
    const int clog = (l & 7) ^ r8;              // pre-swizzled source chunk
    const unsigned short* aS0 = A  + (size_t)(tileM + 8 * w + r8) * DIM + clog * 8;
    const unsigned short* aS1 = aS0 + (size_t)64 * DIM;
    const unsigned short* bS0 = Bm + (size_t)(tileN + 32 * w + r8) * DIM + clog * 8;

#define STAGE(z, s) do {                                                   \
    gload16(aS0 +                (size_t)(s) * BK, (z) + w * 1024);        \
    gload16(aS1 +                (size_t)(s) * BK, (z) + 8192 + w * 1024); \
    gload16(bS0 +                (size_t)(s) * BK, (z) + A_SL + w * 4096);        \
    gload16(bS0 +  8 * DIM +     (size_t)(s) * BK, (z) + A_SL + w * 4096 + 1024); \
    gload16(bS0 + 16 * DIM +     (size_t)(s) * BK, (z) + A_SL + w * 4096 + 2048); \
    gload16(bS0 + 24 * DIM +     (size_t)(s) * BK, (z) + A_SL + w * 4096 + 3072); \
} while (0)

    // ---- frag read offsets: row (l&15), k-chunks swizzled by l&7 ----
    const int rbyte = (l & 15) * 128;
    const int c0 = (((l >> 4)    ) ^ (l & 7)) * 16;   // ks=0
    const int c1 = (((l >> 4) + 4) ^ (l & 7)) * 16;   // ks=1

#define LOADFRAGS(z, A0, A1, B0, B1) do {                            \
    const char* _ab = (z) + wm * 8192 + rbyte;                       \
    A0[0] = *(const bf16x8*)(_ab + 0 * 2048 + c0);                   \
    A1[0] = *(const bf16x8*)(_ab + 0 * 2048 + c1);                   \
    A0[1] = *(const bf16x8*)(_ab + 1 * 2048 + c0);                   \
    A1[1] = *(const bf16x8*)(_ab + 1 * 2048 + c1);                   \
    A0[2] = *(const bf16x8*)(_ab + 2 * 2048 + c0);                   \
    A1[2] = *(const bf16x8*)(_ab + 2 * 2048 + c1);                   \
    A0[3] = *(const bf16x8*)(_ab + 3 * 2048 + c0);                   \
    A1[3] = *(const bf16x8*)(_ab + 3 * 2048 + c1);                   \
    const char* _bb = (z) + A_SL + wn * 8192 + rbyte;                \
    B0[0] = *(const bf16x8*)(_bb + 0 * 2048 + c0);                   \
    B1[0] = *(const bf16x8*)(_bb + 0 * 2048 + c1);                   \
    B0[1] = *(const bf16x8*)(_bb + 1 * 2048 + c0);                   \
    B1[1] = *(const bf16x8*)(_bb + 1 * 2048 + c1);                   \
    B0[2] = *(const bf16x8*)(_bb + 2 * 2048 + c0);                   \
    B1[2] = *(const bf16x8*)(_bb + 2 * 2048 + c1);                   \
    B0[3] = *(const bf16x8*)(_bb + 3 * 2048 + c0);                   \
    B1[3] = *(const bf16x8*)(_bb + 3 * 2048 + c1);                   \
} while (0)

#define PIN(X) asm volatile("" : "+v"(X[0]), "+v"(X[1]), "+v"(X[2]), "+v"(X[3]))

#define MFMA32(A0, A1, B0, B1) do {                                                    \
    _Pragma("unroll")                                                                  \
    for (int _q = 0; _q < 4; ++_q)                                                     \
        _Pragma("unroll")                                                              \
        for (int _j = 0; _j < 4; ++_j) {                                               \
            acc[_q][_j] = __builtin_amdgcn_mfma_f32_16x16x32_bf16(A0[_q], B0[_j],      \
                                                                  acc[_q][_j], 0,0,0); \
            acc[_q][_j] = __builtin_amdgcn_mfma_f32_16x16x32_bf16(A1[_q], B1[_j],      \
                                                                  acc[_q][_j], 0,0,0); \
        }                                                                              \
} while (0)

    bf16x8 Ae0[4], Ae1[4], Be0[4], Be1[4];
    bf16x8 Ao0[4], Ao1[4], Bo0[4], Bo1[4];
    f32x4 acc[4][4] = {};

    char* p0 = smem;
    char* p1 = smem + SLOT;
    char* p2 = smem + 2 * SLOT;

    // ---- prologue ----
    STAGE(p0, 0);
    STAGE(p1, 1);
    asm volatile("s_waitcnt vmcnt(6)" ::: "memory");   // slot0 landed, stage(1) flying
    __builtin_amdgcn_sched_barrier(0);
    __builtin_amdgcn_s_barrier();
    LOADFRAGS(p0, Ae0, Ae1, Be0, Be1);
    PIN(Ae0); PIN(Ae1); PIN(Be0); PIN(Be1);
    asm volatile("s_waitcnt lgkmcnt(0)" ::: "memory");
    __builtin_amdgcn_sched_barrier(0);

#define BODY(CURA0, CURA1, CURB0, CURB1, NXTA0, NXTA1, NXTB0, NXTB1, S) do {  \
    STAGE(p2, (S) + 2);                                                        \
    __builtin_amdgcn_sched_barrier(0);                                         \
    asm volatile("s_waitcnt vmcnt(6)" ::: "memory");                           \
    __builtin_amdgcn_sched_barrier(0);                                         \
    __builtin_amdgcn_s_barrier();                                              \
    LOADFRAGS(p1, NXTA0, NXTA1, NXTB0, NXTB1);                                 \
    PIN(NXTA0); PIN(NXTA1); PIN(NXTB0); PIN(NXTB1);                            \
    __builtin_amdgcn_sched_barrier(0);                                         \
    __builtin_amdgcn_s_setprio(1);                                             \
    MFMA32(CURA0, CURA1, CURB0, CURB1);                                        \
    __builtin_amdgcn_s_setprio(0);                                             \
    asm volatile("s_waitcnt lgkmcnt(0)" ::: "memory");                         \
    __builtin_amdgcn_sched_barrier(0);                                         \
    { char* _t = p0; p0 = p1; p1 = p2; p2 = _t; }                              \
} while (0)

    // ---- main loop: steps 0..29 as 15 even/odd pairs ----
    for (int t = 0; t < 15; ++t) {
        const int s = 2 * t;
        BODY(Ae0, Ae1, Be0, Be1, Ao0, Ao1, Bo0, Bo1, s);       // step s
        BODY(Ao0, Ao1, Bo0, Bo1, Ae0, Ae1, Be0, Be1, s + 1);   // step s+1
    }
    // ---- tail: step 30 (drain stage(31), read slot31, compute E) ----
    asm volatile("s_waitcnt vmcnt(0)" ::: "memory");
    __builtin_amdgcn_sched_barrier(0);
    __builtin_amdgcn_s_barrier();
    LOADFRAGS(p1, Ao0, Ao1, Bo0, Bo1);
    PIN(Ao0); PIN(Ao1); PIN(Bo0); PIN(Bo1);
    __builtin_amdgcn_sched_barrier(0);
    __builtin_amdgcn_s_setprio(1);
    MFMA32(Ae0, Ae1, Be0, Be1);
    __builtin_amdgcn_s_setprio(0);
    asm volatile("s_waitcnt lgkmcnt(0)" ::: "memory");
    __builtin_amdgcn_sched_barrier(0);
    // step 31
    MFMA32(Ao0, Ao1, Bo0, Bo1);

    // ---- epilogue: C = acc + bias ----
    #pragma unroll
    for (int j = 0; j < 4; ++j) {
        int col = tileN + wn * 64 + j * 16 + (l & 15);
        float bj = bias[col];
        #pragma unroll
        for (int i = 0; i < 4; ++i) {
            int rw = tileM + wm * 64 + i * 16 + (l >> 4) * 4;
            #pragma unroll
            for (int r = 0; r < 4; ++r)
                C[(size_t)(rw + r) * DIM + col] = acc[i][j][r] + bj;
        }
    }
}

extern "C" void kernel_launch(void* const* d_in, const int* in_sizes, int n_in,
                              void* d_out, int out_size, void* d_ws, size_t ws_size,
                              hipStream_t stream) {
    const float* x     = (const float*)d_in[0];
    const int*   rows0 = (const int*)  d_in[1];
    const int*   cols0 = (const int*)  d_in[2];
    const float* vals0 = (const float*)d_in[3];
    const int*   rows1 = (const int*)  d_in[4];
    const int*   cols1 = (const int*)  d_in[5];
    const float* vals1 = (const float*)d_in[6];
    const int*   rows2 = (const int*)  d_in[7];
    const int*   cols2 = (const int*)  d_in[8];
    const float* vals2 = (const float*)d_in[9];
    const float* bias  = (const float*)d_in[10];
    float* out = (float*)d_out;

    char* ws = (char*)d_ws;
    unsigned short* Mc = (unsigned short*)ws;                 // 8 MB
    unsigned short* Xb = (unsigned short*)(ws + 8388608);     // 16 MB
    int*   offb = (int*)(ws + 25165824);      // 3 * 2052
    int*   colb = offb + 3 * 2052;            // 3 * 16384
    float* valb = (float*)(colb + 3 * NNZc);  // 3 * 16384

    csr3_kernel<<<3, 1024, 0, stream>>>(rows0, cols0, vals0,
                                        rows1, cols1, vals1,
                                        rows2, cols2, vals2,
                                        offb, colb, valb);
    mcbuild_kernel<<<DIM / RPB, NT, 0, stream>>>(offb, colb, valb, Mc);
    xconv_kernel<<<(BATCH * DIM) / (NT * 8), NT, 0, stream>>>(x, Xb);

    (void)hipFuncSetAttribute((const void*)gemm8,
                              hipFuncAttributeMaxDynamicSharedMemorySize, GEMM_LDS);
    dim3 ggrid(DIM / BN, BATCH / BM);   // 8 x 32 = 256 blocks
    gemm8<<<ggrid, 512, GEMM_LDS, stream>>>(Xb, Mc, bias, out);
}

// Round 11
// 80.408 us; speedup vs baseline: 1.6416x; 1.2283x over previous
//
#include <hip/hip_runtime.h>

// SparseProductLayer:  out = x @ (M0*M1*M2)^T + bias
// Pipeline: multi-block CSR build (memset+hist+shuffle-scan+scatter) ->
// entry-wise Mc build -> x->bf16 -> MFMA GEMM (BM=128,BN=256,BK=64, 3-slot
// LDS ring 144 KB, ONE barrier/K-step, counted vmcnt(6), pinned frag
// double-buffer, chunk^row&7 swizzle, setprio). 256 blocks = 1/CU.
//
// d_ws layout (bytes):
//   [0)         Mc  bf16 [D][D]     8388608
//   [8388608)   Xb  bf16 [B][D]    16777216
//   [25165824)  CSR: off[3][2052], cur[3][2048], col[3][16384], val[3][16384]

#define BATCH 4096
#define DIM   2048
#define NNZc  16384
#define NT    256

typedef short bf16x8 __attribute__((ext_vector_type(8)));
typedef float f32x4  __attribute__((ext_vector_type(4)));

__device__ __forceinline__ unsigned short f2bf(float f) {
    unsigned u = __float_as_uint(f);
    unsigned r = (u + 0x7fffu + ((u >> 16) & 1u)) >> 16;   // RNE
    return (unsigned short)r;
}

__device__ __forceinline__ void gload16(const void* g, void* l) {
    __builtin_amdgcn_global_load_lds((const __attribute__((address_space(1))) void*)g,
                                     (__attribute__((address_space(3))) void*)l, 16, 0, 0);
}

// ---- CSR build: histogram (all 3 matrices, multi-block) ----
__global__ void hist_kernel(const int* __restrict__ rows0, const int* __restrict__ rows1,
                            const int* __restrict__ rows2, int* __restrict__ cur) {
    int e = blockIdx.x * NT + threadIdx.x;          // 0 .. 3*NNZ
    int m = e >> 14, i = e & (NNZc - 1);
    const int* rp = (m == 0) ? rows0 : (m == 1) ? rows1 : rows2;
    atomicAdd(&cur[m * DIM + rp[i]], 1);
}

// ---- CSR build: exclusive scan of 2048 counts (parallel shuffle scan) ----
__global__ void scan_kernel(int* __restrict__ curb, int* __restrict__ offb) {
    int* cur = curb + blockIdx.x * DIM;
    int* off = offb + blockIdx.x * 2052;
    __shared__ int wsum[4];
    int t = threadIdx.x;
    int c[8]; int s = 0;
    #pragma unroll
    for (int i = 0; i < 8; ++i) { c[i] = cur[t * 8 + i]; s += c[i]; }
    int l = t & 63, wv = t >> 6;
    int v = s;
    #pragma unroll
    for (int d = 1; d < 64; d <<= 1) {
        int u = __shfl_up(v, d, 64);
        if (l >= d) v += u;
    }
    if (l == 63) wsum[wv] = v;
    __syncthreads();
    int wbase = 0;
    for (int i = 0; i < wv; ++i) wbase += wsum[i];
    int base = wbase + v - s;     // exclusive prefix for this thread's 8 bins
    #pragma unroll
    for (int i = 0; i < 8; ++i) {
        int idx = t * 8 + i;
        off[idx] = base; cur[idx] = base; base += c[i];
    }
    if (t == 0) off[DIM] = NNZc;
}

// ---- CSR build: scatter entries into row buckets ----
__global__ void scatter_kernel(const int* __restrict__ rows0, const int* __restrict__ cols0,
                               const float* __restrict__ vals0,
                               const int* __restrict__ rows1, const int* __restrict__ cols1,
                               const float* __restrict__ vals1,
                               const int* __restrict__ rows2, const int* __restrict__ cols2,
                               const float* __restrict__ vals2,
                               int* __restrict__ cur,
                               int* __restrict__ colb, float* __restrict__ valb) {
    int e = blockIdx.x * NT + threadIdx.x;
    int m = e >> 14, i = e & (NNZc - 1);
    const int*   rp = (m == 0) ? rows0 : (m == 1) ? rows1 : rows2;
    const int*   cp = (m == 0) ? cols0 : (m == 1) ? cols1 : cols2;
    const float* vp = (m == 0) ? vals0 : (m == 1) ? vals1 : vals2;
    int slot = atomicAdd(&cur[m * DIM + rp[i]], 1);
    colb[m * NNZc + slot] = cp[i];
    valb[m * NNZc + slot] = vp[i];
}

// ---- Mc build: per block, RPB output rows via 3-level tree walk in LDS ----
#define RPB  2
#define PCAP 2048
__global__ __launch_bounds__(NT) void mcbuild_kernel(
        const int* __restrict__ offb, const int* __restrict__ colb,
        const float* __restrict__ valb, unsigned short* __restrict__ Mc) {
    const int* off0 = offb;              const int* off1 = offb + 2052;  const int* off2 = offb + 4104;
    const int* col0 = colb;              const int* col1 = colb + NNZc;  const int* col2 = colb + 2 * NNZc;
    const float* val0 = valb;            const float* val1 = valb + NNZc; const float* val2 = valb + 2 * NNZc;

    __shared__ float acc[RPB * DIM];
    __shared__ int   pk[PCAP];
    __shared__ float pw[PCAP];
    __shared__ int   npairs;

    const int tid = threadIdx.x;
    const int r0  = blockIdx.x * RPB;

    f32x4* az = (f32x4*)acc;
    #pragma unroll
    for (int j = tid; j < RPB * DIM / 4; j += NT) az[j] = (f32x4){0.f, 0.f, 0.f, 0.f};
    if (tid == 0) npairs = 0;
    __syncthreads();

    #pragma unroll
    for (int k = 0; k < RPB; ++k) {
        int b = off0[r0 + k], e = off0[r0 + k + 1];
        for (int i = b + tid; i < e; i += NT) {
            int   c0 = col0[i];
            float v0 = val0[i];
            int b1 = off1[c0], e1 = off1[c0 + 1];
            for (int j = b1; j < e1; ++j) {
                float w = v0 * val1[j];
                int   c1 = col1[j];
                int slot = atomicAdd(&npairs, 1);
                if (slot < PCAP) { pk[slot] = (k << 16) | c1; pw[slot] = w; }
                else {
                    int b2 = off2[c1], e2 = off2[c1 + 1];
                    for (int q = b2; q < e2; ++q)
                        atomicAdd(&acc[k * DIM + col2[q]], w * val2[q]);
                }
            }
        }
    }
    __syncthreads();

    int np = min(npairs, PCAP);
    for (int p = tid; p < np; p += NT) {
        int   k  = pk[p] >> 16, c1 = pk[p] & 0xffff;
        float w  = pw[p];
        int b2 = off2[c1], e2 = off2[c1 + 1];
        for (int q = b2; q < e2; ++q)
            atomicAdd(&acc[k * DIM + col2[q]], w * val2[q]);
    }
    __syncthreads();

    #pragma unroll
    for (int k = 0; k < RPB; ++k) {
        unsigned short o[8];
        #pragma unroll
        for (int jj = 0; jj < 8; ++jj) o[jj] = f2bf(acc[k * DIM + tid * 8 + jj]);
        *(ulonglong2*)(Mc + (size_t)(r0 + k) * DIM + tid * 8) = *(ulonglong2*)o;
    }
}

// ---- x (f32) -> bf16, linear layout ----
__global__ void xconv_kernel(const float* __restrict__ x, unsigned short* __restrict__ Xb) {
    size_t i = ((size_t)blockIdx.x * NT + threadIdx.x) * 8;
    float4 a = *(const float4*)(x + i);
    float4 b = *(const float4*)(x + i + 4);
    unsigned short o[8] = {f2bf(a.x), f2bf(a.y), f2bf(a.z), f2bf(a.w),
                           f2bf(b.x), f2bf(b.y), f2bf(b.z), f2bf(b.w)};
    *(ulonglong2*)(Xb + i) = *(ulonglong2*)o;
}

// ---- GEMM: C = Xb(4096x2048) @ Mc^T + bias ----
// 3-slot ring, BK=64. LDS slot: A [128 rows][64 k] (128-B rows, 16 KB) then
// B [256][64] (32 KB). Swizzle: phys 16B-chunk = logical ^ (row&7).
// Per step/wave: 6 gload_lds (stage s+2) + 16 ds_read_b128 (frags s+1,
// pinned, overlap MFMA s) + 32 MFMA. One barrier/step, vmcnt(6).
#define BM 128
#define BN 256
#define BK 64
#define NS (DIM / BK)                   // 32
#define A_SL (BM * BK * 2)              // 16384
#define B_SL (BN * BK * 2)              // 32768
#define SLOT (A_SL + B_SL)              // 49152
#define GEMM_LDS (3 * SLOT)             // 147456

__global__ __launch_bounds__(512, 2) void gemm8(
        const unsigned short* __restrict__ A,   // Xb [4096][2048]
        const unsigned short* __restrict__ Bm,  // Mc [2048][2048]
        const float* __restrict__ bias,
        float* __restrict__ C) {
    extern __shared__ char smem[];
    const int tid = threadIdx.x;
    const int l = tid & 63, w = tid >> 6;
    const int wm = w & 1, wn = w >> 1;          // 2M x 4N wave grid, tile 64x64
    const int tileM = blockIdx.y * BM;
    const int tileN = blockIdx.x * BN;

    // ---- staging: lane l covers row-in-8 (l>>3), phys chunk l&7 ----
    const int r8   = l >> 3;
    const int clog = (l & 7) ^ r8;              // pre-swizzled source chunk
    const unsigned short* aS0 = A  + (size_t)(tileM + 8 * w + r8) * DIM + clog * 8;
    const unsigned short* aS1 = aS0 + (size_t)64 * DIM;
    const unsigned short* bS0 = Bm + (size_t)(tileN + 32 * w + r8) * DIM + clog * 8;

#define STAGE(z, s) do {                                                   \
    gload16(aS0 +                (size_t)(s) * BK, (z) + w * 1024);        \
    gload16(aS1 +                (size_t)(s) * BK, (z) + 8192 + w * 1024); \
    gload16(bS0 +                (size_t)(s) * BK, (z) + A_SL + w * 4096);        \
    gload16(bS0 +  8 * DIM +     (size_t)(s) * BK, (z) + A_SL + w * 4096 + 1024); \
    gload16(bS0 + 16 * DIM +     (size_t)(s) * BK, (z) + A_SL + w * 4096 + 2048); \
    gload16(bS0 + 24 * DIM +     (size_t)(s) * BK, (z) + A_SL + w * 4096 + 3072); \
} while (0)

    // ---- frag read offsets: row (l&15), k-chunks swizzled by l&7 ----
    const int rbyte = (l & 15) * 128;
    const int c0 = (((l >> 4)    ) ^ (l & 7)) * 16;   // ks=0
    const int c1 = (((l >> 4) + 4) ^ (l & 7)) * 16;   // ks=1

#define LOADFRAGS(z, A0, A1, B0, B1) do {                            \
    const char* _ab = (z) + wm * 8192 + rbyte;                       \
    A0[0] = *(const bf16x8*)(_ab + 0 * 2048 + c0);                   \
    A1[0] = *(const bf16x8*)(_ab + 0 * 2048 + c1);                   \
    A0[1] = *(const bf16x8*)(_ab + 1 * 2048 + c0);                   \
    A1[1] = *(const bf16x8*)(_ab + 1 * 2048 + c1);                   \
    A0[2] = *(const bf16x8*)(_ab + 2 * 2048 + c0);                   \
    A1[2] = *(const bf16x8*)(_ab + 2 * 2048 + c1);                   \
    A0[3] = *(const bf16x8*)(_ab + 3 * 2048 + c0);                   \
    A1[3] = *(const bf16x8*)(_ab + 3 * 2048 + c1);                   \
    const char* _bb = (z) + A_SL + wn * 8192 + rbyte;                \
    B0[0] = *(const bf16x8*)(_bb + 0 * 2048 + c0);                   \
    B1[0] = *(const bf16x8*)(_bb + 0 * 2048 + c1);                   \
    B0[1] = *(const bf16x8*)(_bb + 1 * 2048 + c0);                   \
    B1[1] = *(const bf16x8*)(_bb + 1 * 2048 + c1);                   \
    B0[2] = *(const bf16x8*)(_bb + 2 * 2048 + c0);                   \
    B1[2] = *(const bf16x8*)(_bb + 2 * 2048 + c1);                   \
    B0[3] = *(const bf16x8*)(_bb + 3 * 2048 + c0);                   \
    B1[3] = *(const bf16x8*)(_bb + 3 * 2048 + c1);                   \
} while (0)

#define PIN(X) asm volatile("" : "+v"(X[0]), "+v"(X[1]), "+v"(X[2]), "+v"(X[3]))

#define MFMA32(A0, A1, B0, B1) do {                                                    \
    _Pragma("unroll")                                                                  \
    for (int _q = 0; _q < 4; ++_q)                                                     \
        _Pragma("unroll")                                                              \
        for (int _j = 0; _j < 4; ++_j) {                                               \
            acc[_q][_j] = __builtin_amdgcn_mfma_f32_16x16x32_bf16(A0[_q], B0[_j],      \
                                                                  acc[_q][_j], 0,0,0); \
            acc[_q][_j] = __builtin_amdgcn_mfma_f32_16x16x32_bf16(A1[_q], B1[_j],      \
                                                                  acc[_q][_j], 0,0,0); \
        }                                                                              \
} while (0)

    bf16x8 Ae0[4], Ae1[4], Be0[4], Be1[4];
    bf16x8 Ao0[4], Ao1[4], Bo0[4], Bo1[4];
    f32x4 acc[4][4] = {};

    char* p0 = smem;
    char* p1 = smem + SLOT;
    char* p2 = smem + 2 * SLOT;

    // ---- prologue ----
    STAGE(p0, 0);
    STAGE(p1, 1);
    asm volatile("s_waitcnt vmcnt(6)" ::: "memory");   // slot0 landed, stage(1) flying
    __builtin_amdgcn_sched_barrier(0);
    __builtin_amdgcn_s_barrier();
    LOADFRAGS(p0, Ae0, Ae1, Be0, Be1);
    PIN(Ae0); PIN(Ae1); PIN(Be0); PIN(Be1);
    asm volatile("s_waitcnt lgkmcnt(0)" ::: "memory");
    __builtin_amdgcn_sched_barrier(0);

#define BODY(CURA0, CURA1, CURB0, CURB1, NXTA0, NXTA1, NXTB0, NXTB1, S) do {  \
    STAGE(p2, (S) + 2);                                                        \
    __builtin_amdgcn_sched_barrier(0);                                         \
    asm volatile("s_waitcnt vmcnt(6)" ::: "memory");                           \
    __builtin_amdgcn_sched_barrier(0);                                         \
    __builtin_amdgcn_s_barrier();                                              \
    LOADFRAGS(p1, NXTA0, NXTA1, NXTB0, NXTB1);                                 \
    PIN(NXTA0); PIN(NXTA1); PIN(NXTB0); PIN(NXTB1);                            \
    __builtin_amdgcn_sched_barrier(0);                                         \
    __builtin_amdgcn_s_setprio(1);                                             \
    MFMA32(CURA0, CURA1, CURB0, CURB1);                                        \
    __builtin_amdgcn_s_setprio(0);                                             \
    asm volatile("s_waitcnt lgkmcnt(0)" ::: "memory");                         \
    __builtin_amdgcn_sched_barrier(0);                                         \
    { char* _t = p0; p0 = p1; p1 = p2; p2 = _t; }                              \
} while (0)

    // ---- main loop: steps 0..29 as 15 even/odd pairs ----
    for (int t = 0; t < 15; ++t) {
        const int s = 2 * t;
        BODY(Ae0, Ae1, Be0, Be1, Ao0, Ao1, Bo0, Bo1, s);       // step s
        BODY(Ao0, Ao1, Bo0, Bo1, Ae0, Ae1, Be0, Be1, s + 1);   // step s+1
    }
    // ---- tail: step 30 (drain stage(31), read slot31, compute E) ----
    asm volatile("s_waitcnt vmcnt(0)" ::: "memory");
    __builtin_amdgcn_sched_barrier(0);
    __builtin_amdgcn_s_barrier();
    LOADFRAGS(p1, Ao0, Ao1, Bo0, Bo1);
    PIN(Ao0); PIN(Ao1); PIN(Bo0); PIN(Bo1);
    __builtin_amdgcn_sched_barrier(0);
    __builtin_amdgcn_s_setprio(1);
    MFMA32(Ae0, Ae1, Be0, Be1);
    __builtin_amdgcn_s_setprio(0);
    asm volatile("s_waitcnt lgkmcnt(0)" ::: "memory");
    __builtin_amdgcn_sched_barrier(0);
    // step 31
    MFMA32(Ao0, Ao1, Bo0, Bo1);

    // ---- epilogue: C = acc + bias ----
    #pragma unroll
    for (int j = 0; j < 4; ++j) {
        int col = tileN + wn * 64 + j * 16 + (l & 15);
        float bj = bias[col];
        #pragma unroll
        for (int i = 0; i < 4; ++i) {
            int rw = tileM + wm * 64 + i * 16 + (l >> 4) * 4;
            #pragma unroll
            for (int r = 0; r < 4; ++r)
                C[(size_t)(rw + r) * DIM + col] = acc[i][j][r] + bj;
        }
    }
}

extern "C" void kernel_launch(void* const* d_in, const int* in_sizes, int n_in,
                              void* d_out, int out_size, void* d_ws, size_t ws_size,
                              hipStream_t stream) {
    const float* x     = (const float*)d_in[0];
    const int*   rows0 = (const int*)  d_in[1];
    const int*   cols0 = (const int*)  d_in[2];
    const float* vals0 = (const float*)d_in[3];
    const int*   rows1 = (const int*)  d_in[4];
    const int*   cols1 = (const int*)  d_in[5];
    const float* vals1 = (const float*)d_in[6];
    const int*   rows2 = (const int*)  d_in[7];
    const int*   cols2 = (const int*)  d_in[8];
    const float* vals2 = (const float*)d_in[9];
    const float* bias  = (const float*)d_in[10];
    float* out = (float*)d_out;

    char* ws = (char*)d_ws;
    unsigned short* Mc = (unsigned short*)ws;                 // 8 MB
    unsigned short* Xb = (unsigned short*)(ws + 8388608);     // 16 MB
    int*   offb = (int*)(ws + 25165824);      // 3 * 2052
    int*   curb = offb + 3 * 2052;            // 3 * 2048
    int*   colb = curb + 3 * DIM;             // 3 * 16384
    float* valb = (float*)(colb + 3 * NNZc);  // 3 * 16384

    hipMemsetAsync(curb, 0, 3 * DIM * sizeof(int), stream);

    hist_kernel<<<3 * NNZc / NT, NT, 0, stream>>>(rows0, rows1, rows2, curb);
    scan_kernel<<<3, NT, 0, stream>>>(curb, offb);
    scatter_kernel<<<3 * NNZc / NT, NT, 0, stream>>>(rows0, cols0, vals0,
                                                     rows1, cols1, vals1,
                                                     rows2, cols2, vals2,
                                                     curb, colb, valb);
    mcbuild_kernel<<<DIM / RPB, NT, 0, stream>>>(offb, colb, valb, Mc);
    xconv_kernel<<<(BATCH * DIM) / (NT * 8), NT, 0, stream>>>(x, Xb);

    (void)hipFuncSetAttribute((const void*)gemm8,
                              hipFuncAttributeMaxDynamicSharedMemorySize, GEMM_LDS);
    dim3 ggrid(DIM / BN, BATCH / BM);   // 8 x 32 = 256 blocks
    gemm8<<<ggrid, 512, GEMM_LDS, stream>>>(Xb, Mc, bias, out);
}